// Round 1
// baseline (1503.504 us; speedup 1.0000x reference)
//
#include <hip/hip_runtime.h>
#include <stddef.h>

// Problem constants (match reference setup_inputs)
constexpr int N_NODES = 200000;
constexpr int N_EDGES = 200000;
constexpr int N_GRAPHS = 128;
constexpr int IN_F = 256;
constexpr int HID_F = 128;
constexpr int OUT_F = 128;
constexpr int OUT_W = OUT_F + HID_F; // 256 output cols per graph

// ---------------- small utility kernels ----------------

__global__ void fill1_kernel(float* __restrict__ p, int n) {
    int i = blockIdx.x * blockDim.x + threadIdx.x;
    if (i < n) p[i] = 1.0f;
}

__global__ void deg_edges_kernel(const int* __restrict__ dst, float* __restrict__ deg, int E) {
    int e = blockIdx.x * blockDim.x + threadIdx.x;
    if (e < E) atomicAdd(&deg[dst[e]], 1.0f);
}

__global__ void count_kernel(const int* __restrict__ batch, int* __restrict__ cnt, int n) {
    int i = blockIdx.x * blockDim.x + threadIdx.x;
    if (i < n) atomicAdd(&cnt[batch[i]], 1);
}

// start[g] = sum_{j<g} cnt[j]; single block of N_GRAPHS threads
__global__ void scan_kernel(const int* __restrict__ cnt, int* __restrict__ start, int G) {
    int g = threadIdx.x;
    if (g < G) {
        int s = 0;
        for (int j = 0; j < g; ++j) s += cnt[j];
        start[g] = s;
    }
}

// ---------------- GEMM: C[M,Nout] = op(A)[M,K] @ B[K,Nout] (+ rootlin[batch[row]]) ----------------
// op = relu if reluA. 64x64 tile, 256 threads, 4x4 microtile. M%64==0, K%16==0, Nout%64==0.

__global__ __launch_bounds__(256) void gemm_kernel(
    const float* __restrict__ A, const float* __restrict__ Bm, float* __restrict__ C,
    int M, int K, int Nout, int reluA,
    const float* __restrict__ rootlin, const int* __restrict__ batch)
{
    __shared__ float As[16][64];
    __shared__ float Bs[16][64];

    const int tid = threadIdx.x;
    const int tm = tid >> 4;          // 0..15
    const int tn = tid & 15;          // 0..15
    const int row0 = blockIdx.x * 64;
    const int col0 = blockIdx.y * 64;

    // A-tile load mapping: thread loads one float4 = A[row0 + a_m][k0 + a_k4 .. +3]
    const int a_m = tid >> 2;         // 0..63
    const int a_k4 = (tid & 3) * 4;   // 0,4,8,12
    // B-tile load mapping: thread loads one float4 = B[k0 + b_k][col0 + b_n4 .. +3]
    const int b_k = tid >> 4;         // 0..15
    const int b_n4 = (tid & 15) * 4;  // 0..60

    float acc[4][4] = {};

    for (int k0 = 0; k0 < K; k0 += 16) {
        float4 av = *(const float4*)(A + (size_t)(row0 + a_m) * K + (k0 + a_k4));
        if (reluA) {
            av.x = fmaxf(av.x, 0.f); av.y = fmaxf(av.y, 0.f);
            av.z = fmaxf(av.z, 0.f); av.w = fmaxf(av.w, 0.f);
        }
        As[a_k4 + 0][a_m] = av.x;
        As[a_k4 + 1][a_m] = av.y;
        As[a_k4 + 2][a_m] = av.z;
        As[a_k4 + 3][a_m] = av.w;
        *(float4*)&Bs[b_k][b_n4] = *(const float4*)(Bm + (size_t)(k0 + b_k) * Nout + (col0 + b_n4));
        __syncthreads();
        #pragma unroll
        for (int kk = 0; kk < 16; ++kk) {
            float a[4], b[4];
            *(float4*)a = *(const float4*)&As[kk][tm * 4];
            *(float4*)b = *(const float4*)&Bs[kk][tn * 4];
            #pragma unroll
            for (int r = 0; r < 4; ++r)
                #pragma unroll
                for (int c = 0; c < 4; ++c)
                    acc[r][c] += a[r] * b[c];
        }
        __syncthreads();
    }

    #pragma unroll
    for (int r = 0; r < 4; ++r) {
        int row = row0 + tm * 4 + r;
        float4 v = make_float4(acc[r][0], acc[r][1], acc[r][2], acc[r][3]);
        if (rootlin != nullptr) {
            int g = batch[row];
            float4 rl = *(const float4*)&rootlin[(size_t)g * Nout + col0 + tn * 4];
            v.x += rl.x; v.y += rl.y; v.z += rl.z; v.w += rl.w;
        }
        *(float4*)&C[(size_t)row * Nout + col0 + tn * 4] = v;
    }
}

// rootlin[g,f] = sum_k relu(x[root_index[g],k]) * W2[(HID_F+k)*OUT_F + f]
__global__ void rootlin_kernel(const float* __restrict__ x, const int* __restrict__ root_index,
                               const float* __restrict__ W2, float* __restrict__ rootlin)
{
    int g = blockIdx.x;
    int f = threadIdx.x; // OUT_F threads
    int r = root_index[g];
    const float* xr = x + (size_t)r * IN_F;
    float acc = 0.f;
    for (int k = 0; k < IN_F; ++k) {
        float xv = fmaxf(xr[k], 0.f);
        acc += xv * W2[(size_t)(HID_F + k) * OUT_F + f];
    }
    rootlin[(size_t)g * OUT_F + f] = acc;
}

// agg[dst[e], f] += h[src[e], f] * rsqrt(deg[src]) * rsqrt(deg[dst]); F = 128 fixed
__global__ __launch_bounds__(256) void scatter_kernel(
    const float* __restrict__ h, const int* __restrict__ src, const int* __restrict__ dst,
    const float* __restrict__ deg, float* __restrict__ agg, int E)
{
    int t = blockIdx.x * 256 + threadIdx.x;
    int e = t >> 7;
    int f = t & 127;
    if (e >= E) return;
    int s = src[e], d = dst[e];
    float norm = rsqrtf(deg[s]) * rsqrtf(deg[d]);
    atomicAdd(&agg[(size_t)d * 128 + f], h[(size_t)s * 128 + f] * norm);
}

// out[i] = agg[i] + h[i]/deg[node] + b[f]   (float4 over N*128)
__global__ __launch_bounds__(256) void finalize1_kernel(
    const float* __restrict__ agg, const float* __restrict__ h, const float* __restrict__ deg,
    const float* __restrict__ b, float* __restrict__ outb, int total4)
{
    int t = blockIdx.x * 256 + threadIdx.x;
    if (t >= total4) return;
    int node = t >> 5;            // 32 float4 per 128-wide row
    int f4 = (t & 31) * 4;
    float inv = 1.0f / deg[node];
    float4 a = *(const float4*)(agg + (size_t)t * 4);
    float4 hv = *(const float4*)(h + (size_t)t * 4);
    float4 bv = *(const float4*)(b + f4);
    float4 o;
    o.x = a.x + hv.x * inv + bv.x;
    o.y = a.y + hv.y * inv + bv.y;
    o.z = a.z + hv.z * inv + bv.z;
    o.w = a.w + hv.w * inv + bv.w;
    *(float4*)(outb + (size_t)t * 4) = o;
}

// h[i] = relu(agg[i] + h[i]/deg[node] + b[f])   (in-place on h)
__global__ __launch_bounds__(256) void finalize2_kernel(
    const float* __restrict__ agg, float* __restrict__ h, const float* __restrict__ deg,
    const float* __restrict__ b, int total4)
{
    int t = blockIdx.x * 256 + threadIdx.x;
    if (t >= total4) return;
    int node = t >> 5;
    int f4 = (t & 31) * 4;
    float inv = 1.0f / deg[node];
    float4 a = *(const float4*)(agg + (size_t)t * 4);
    float4 hv = *(const float4*)(h + (size_t)t * 4);
    float4 bv = *(const float4*)(b + f4);
    float4 o;
    o.x = fmaxf(a.x + hv.x * inv + bv.x, 0.f);
    o.y = fmaxf(a.y + hv.y * inv + bv.y, 0.f);
    o.z = fmaxf(a.z + hv.z * inv + bv.z, 0.f);
    o.w = fmaxf(a.w + hv.w * inv + bv.w, 0.f);
    *(float4*)(h + (size_t)t * 4) = o;
}

// out[g, 0:128] = mean over segment of h2relu; out[g, 128:256] = cnt>0 ? x2[root_g] : 0
// grid (G, CHUNKS), 128 threads. out must be pre-zeroed.
__global__ void mean_kernel(const float* __restrict__ h2, const float* __restrict__ x2,
                            const int* __restrict__ root_index, const int* __restrict__ cnt,
                            const int* __restrict__ start, float* __restrict__ out, int chunks)
{
    int g = blockIdx.x;
    int c = blockIdx.y;
    int f = threadIdx.x; // 128
    int s = start[g], n = cnt[g];
    int per = (n + chunks - 1) / chunks;
    int lo = s + c * per;
    int hi = min(s + n, lo + per);
    float acc = 0.f;
    for (int i = lo; i < hi; ++i) acc += h2[(size_t)i * 128 + f];
    float inv = 1.0f / (float)max(n, 1);
    atomicAdd(&out[(size_t)g * OUT_W + f], acc * inv);
    if (c == 0) {
        float v = (n > 0) ? x2[(size_t)root_index[g] * 128 + f] : 0.f;
        out[(size_t)g * OUT_W + HID_F + f] = v;
    }
}

// ---------------- launch ----------------

static inline size_t align_up(size_t x, size_t a) { return (x + a - 1) / a * a; }

extern "C" void kernel_launch(void* const* d_in, const int* in_sizes, int n_in,
                              void* d_out, int out_size, void* d_ws, size_t ws_size,
                              hipStream_t stream) {
    const float* x = (const float*)d_in[0];
    const int* ei = (const int*)d_in[1];
    const int* batch = (const int*)d_in[2];
    const int* root = (const int*)d_in[3];
    const float* W1 = (const float*)d_in[4];
    const float* b1 = (const float*)d_in[5];
    const float* W2 = (const float*)d_in[6];
    const float* b2 = (const float*)d_in[7];
    float* out = (float*)d_out;

    const int* src = ei;
    const int* dst = ei + N_EDGES;

    // workspace carve-up
    char* ws = (char*)d_ws;
    size_t off = 0;
    const size_t NB = (size_t)N_NODES * 128 * sizeof(float); // 102.4 MB

    float* deg = (float*)(ws + off); off = align_up(off + (size_t)N_NODES * sizeof(float), 256);
    int* cnt = (int*)(ws + off);     off = align_up(off + N_GRAPHS * sizeof(int), 256);
    int* startv = (int*)(ws + off);  off = align_up(off + N_GRAPHS * sizeof(int), 256);
    float* rootlin = (float*)(ws + off); off = align_up(off + (size_t)N_GRAPHS * OUT_F * sizeof(float), 256);
    float* buf0 = (float*)(ws + off); off = align_up(off + NB, 256); // h0 -> hlin -> h2relu
    float* buf1 = (float*)(ws + off); off = align_up(off + NB, 256); // agg (both convs)
    float* buf2 = (float*)(ws + off); off = align_up(off + NB, 256); // x2
    (void)ws_size; (void)n_in; (void)in_sizes; (void)out_size;

    const int total4 = N_NODES * 32; // N*128/4

    // degree (with self loop) + segment bookkeeping
    fill1_kernel<<<(N_NODES + 255) / 256, 256, 0, stream>>>(deg, N_NODES);
    hipMemsetAsync(cnt, 0, N_GRAPHS * sizeof(int), stream);
    deg_edges_kernel<<<(N_EDGES + 255) / 256, 256, 0, stream>>>(dst, deg, N_EDGES);
    count_kernel<<<(N_NODES + 255) / 256, 256, 0, stream>>>(batch, cnt, N_NODES);
    scan_kernel<<<1, N_GRAPHS, 0, stream>>>(cnt, startv, N_GRAPHS);

    // conv1: h0 = x @ W1
    {
        dim3 grid(N_NODES / 64, HID_F / 64);
        gemm_kernel<<<grid, 256, 0, stream>>>(x, W1, buf0, N_NODES, IN_F, HID_F, 0, nullptr, nullptr);
    }
    hipMemsetAsync(buf1, 0, NB, stream);
    scatter_kernel<<<(N_EDGES * 128) / 256, 256, 0, stream>>>(buf0, src, dst, deg, buf1, N_EDGES);
    finalize1_kernel<<<(total4 + 255) / 256, 256, 0, stream>>>(buf1, buf0, deg, b1, buf2, total4);

    // conv2: hlin = relu(x2) @ W2[0:128] + rootlin[batch]
    rootlin_kernel<<<N_GRAPHS, OUT_F, 0, stream>>>(x, root, W2, rootlin);
    {
        dim3 grid(N_NODES / 64, OUT_F / 64);
        gemm_kernel<<<grid, 256, 0, stream>>>(buf2, W2, buf0, N_NODES, HID_F, OUT_F, 1, rootlin, batch);
    }
    hipMemsetAsync(buf1, 0, NB, stream);
    scatter_kernel<<<(N_EDGES * 128) / 256, 256, 0, stream>>>(buf0, src, dst, deg, buf1, N_EDGES);
    finalize2_kernel<<<(total4 + 255) / 256, 256, 0, stream>>>(buf1, buf0, deg, b2, total4);

    // graph mean + root gather
    hipMemsetAsync(out, 0, (size_t)N_GRAPHS * OUT_W * sizeof(float), stream);
    dim3 mg(N_GRAPHS, 8);
    mean_kernel<<<mg, 128, 0, stream>>>(buf0, buf2, root, cnt, startv, out, 8);
}

// Round 2
// 903.076 us; speedup vs baseline: 1.6649x; 1.6649x over previous
//
#include <hip/hip_runtime.h>
#include <stddef.h>

// Problem constants (match reference setup_inputs)
constexpr int N_NODES = 200000;
constexpr int N_EDGES = 200000;
constexpr int N_GRAPHS = 128;
constexpr int IN_F = 256;
constexpr int HID_F = 128;
constexpr int OUT_F = 128;
constexpr int OUT_W = OUT_F + HID_F; // 256 output cols per graph

// ---------------- small utility kernels ----------------

__global__ void fill1_kernel(float* __restrict__ p, int n) {
    int i = blockIdx.x * blockDim.x + threadIdx.x;
    if (i < n) p[i] = 1.0f;
}

__global__ void deg_edges_kernel(const int* __restrict__ dst, float* __restrict__ deg, int E) {
    int e = blockIdx.x * blockDim.x + threadIdx.x;
    if (e < E) atomicAdd(&deg[dst[e]], 1.0f);
}

// batch is SORTED. start[g] = first i with batch[i] >= g (binary search),
// start[G] = n; cnt[g] = start[g+1] - start[g]. One block, G threads.
// Replaces the 582us atomic-contention count_kernel (Round 1 post-mortem).
__global__ void bounds_kernel(const int* __restrict__ batch, int* __restrict__ start,
                              int* __restrict__ cnt, int n, int G) {
    __shared__ int s_start[N_GRAPHS + 1];
    int g = threadIdx.x;
    if (g < G) {
        int lo = 0, hi = n; // find first index with batch[idx] >= g
        while (lo < hi) {
            int mid = (lo + hi) >> 1;
            if (batch[mid] < g) lo = mid + 1; else hi = mid;
        }
        s_start[g] = lo;
        if (g == 0) s_start[G] = n;
    }
    __syncthreads();
    if (g < G) {
        start[g] = s_start[g];
        cnt[g] = s_start[g + 1] - s_start[g];
    }
}

// ---------------- GEMM: C[M,Nout] = op(A)[M,K] @ B[K,Nout] (+ rootlin[batch[row]]) ----------------
// op = relu if reluA. 64x64 tile, 256 threads, 4x4 microtile. M%64==0, K%16==0, Nout%64==0.

__global__ __launch_bounds__(256) void gemm_kernel(
    const float* __restrict__ A, const float* __restrict__ Bm, float* __restrict__ C,
    int M, int K, int Nout, int reluA,
    const float* __restrict__ rootlin, const int* __restrict__ batch)
{
    __shared__ float As[16][64];
    __shared__ float Bs[16][64];

    const int tid = threadIdx.x;
    const int tm = tid >> 4;          // 0..15
    const int tn = tid & 15;          // 0..15
    const int row0 = blockIdx.x * 64;
    const int col0 = blockIdx.y * 64;

    // A-tile load mapping: thread loads one float4 = A[row0 + a_m][k0 + a_k4 .. +3]
    const int a_m = tid >> 2;         // 0..63
    const int a_k4 = (tid & 3) * 4;   // 0,4,8,12
    // B-tile load mapping: thread loads one float4 = B[k0 + b_k][col0 + b_n4 .. +3]
    const int b_k = tid >> 4;         // 0..15
    const int b_n4 = (tid & 15) * 4;  // 0..60

    float acc[4][4] = {};

    for (int k0 = 0; k0 < K; k0 += 16) {
        float4 av = *(const float4*)(A + (size_t)(row0 + a_m) * K + (k0 + a_k4));
        if (reluA) {
            av.x = fmaxf(av.x, 0.f); av.y = fmaxf(av.y, 0.f);
            av.z = fmaxf(av.z, 0.f); av.w = fmaxf(av.w, 0.f);
        }
        As[a_k4 + 0][a_m] = av.x;
        As[a_k4 + 1][a_m] = av.y;
        As[a_k4 + 2][a_m] = av.z;
        As[a_k4 + 3][a_m] = av.w;
        *(float4*)&Bs[b_k][b_n4] = *(const float4*)(Bm + (size_t)(k0 + b_k) * Nout + (col0 + b_n4));
        __syncthreads();
        #pragma unroll
        for (int kk = 0; kk < 16; ++kk) {
            float a[4], b[4];
            *(float4*)a = *(const float4*)&As[kk][tm * 4];
            *(float4*)b = *(const float4*)&Bs[kk][tn * 4];
            #pragma unroll
            for (int r = 0; r < 4; ++r)
                #pragma unroll
                for (int c = 0; c < 4; ++c)
                    acc[r][c] += a[r] * b[c];
        }
        __syncthreads();
    }

    #pragma unroll
    for (int r = 0; r < 4; ++r) {
        int row = row0 + tm * 4 + r;
        float4 v = make_float4(acc[r][0], acc[r][1], acc[r][2], acc[r][3]);
        if (rootlin != nullptr) {
            int g = batch[row];
            float4 rl = *(const float4*)&rootlin[(size_t)g * Nout + col0 + tn * 4];
            v.x += rl.x; v.y += rl.y; v.z += rl.z; v.w += rl.w;
        }
        *(float4*)&C[(size_t)row * Nout + col0 + tn * 4] = v;
    }
}

// rootlin[g,f] = sum_k relu(x[root_index[g],k]) * W2[(HID_F+k)*OUT_F + f]
__global__ void rootlin_kernel(const float* __restrict__ x, const int* __restrict__ root_index,
                               const float* __restrict__ W2, float* __restrict__ rootlin)
{
    int g = blockIdx.x;
    int f = threadIdx.x; // OUT_F threads
    int r = root_index[g];
    const float* xr = x + (size_t)r * IN_F;
    float acc = 0.f;
    for (int k = 0; k < IN_F; ++k) {
        float xv = fmaxf(xr[k], 0.f);
        acc += xv * W2[(size_t)(HID_F + k) * OUT_F + f];
    }
    rootlin[(size_t)g * OUT_F + f] = acc;
}

// agg[dst[e], f] += h[src[e], f] * rsqrt(deg[src]) * rsqrt(deg[dst]); F = 128 fixed
__global__ __launch_bounds__(256) void scatter_kernel(
    const float* __restrict__ h, const int* __restrict__ src, const int* __restrict__ dst,
    const float* __restrict__ deg, float* __restrict__ agg, int E)
{
    int t = blockIdx.x * 256 + threadIdx.x;
    int e = t >> 7;
    int f = t & 127;
    if (e >= E) return;
    int s = src[e], d = dst[e];
    float norm = rsqrtf(deg[s]) * rsqrtf(deg[d]);
    atomicAdd(&agg[(size_t)d * 128 + f], h[(size_t)s * 128 + f] * norm);
}

// out[i] = agg[i] + h[i]/deg[node] + b[f]   (float4 over N*128)
__global__ __launch_bounds__(256) void finalize1_kernel(
    const float* __restrict__ agg, const float* __restrict__ h, const float* __restrict__ deg,
    const float* __restrict__ b, float* __restrict__ outb, int total4)
{
    int t = blockIdx.x * 256 + threadIdx.x;
    if (t >= total4) return;
    int node = t >> 5;            // 32 float4 per 128-wide row
    int f4 = (t & 31) * 4;
    float inv = 1.0f / deg[node];
    float4 a = *(const float4*)(agg + (size_t)t * 4);
    float4 hv = *(const float4*)(h + (size_t)t * 4);
    float4 bv = *(const float4*)(b + f4);
    float4 o;
    o.x = a.x + hv.x * inv + bv.x;
    o.y = a.y + hv.y * inv + bv.y;
    o.z = a.z + hv.z * inv + bv.z;
    o.w = a.w + hv.w * inv + bv.w;
    *(float4*)(outb + (size_t)t * 4) = o;
}

// h[i] = relu(agg[i] + h[i]/deg[node] + b[f])   (in-place on h)
__global__ __launch_bounds__(256) void finalize2_kernel(
    const float* __restrict__ agg, float* __restrict__ h, const float* __restrict__ deg,
    const float* __restrict__ b, int total4)
{
    int t = blockIdx.x * 256 + threadIdx.x;
    if (t >= total4) return;
    int node = t >> 5;
    int f4 = (t & 31) * 4;
    float inv = 1.0f / deg[node];
    float4 a = *(const float4*)(agg + (size_t)t * 4);
    float4 hv = *(const float4*)(h + (size_t)t * 4);
    float4 bv = *(const float4*)(b + f4);
    float4 o;
    o.x = fmaxf(a.x + hv.x * inv + bv.x, 0.f);
    o.y = fmaxf(a.y + hv.y * inv + bv.y, 0.f);
    o.z = fmaxf(a.z + hv.z * inv + bv.z, 0.f);
    o.w = fmaxf(a.w + hv.w * inv + bv.w, 0.f);
    *(float4*)(h + (size_t)t * 4) = o;
}

// out[g, 0:128] = mean over segment of h2relu; out[g, 128:256] = cnt>0 ? x2[root_g] : 0
// grid (G, CHUNKS), 128 threads. out must be pre-zeroed.
__global__ void mean_kernel(const float* __restrict__ h2, const float* __restrict__ x2,
                            const int* __restrict__ root_index, const int* __restrict__ cnt,
                            const int* __restrict__ start, float* __restrict__ out, int chunks)
{
    int g = blockIdx.x;
    int c = blockIdx.y;
    int f = threadIdx.x; // 128
    int s = start[g], n = cnt[g];
    int per = (n + chunks - 1) / chunks;
    int lo = s + c * per;
    int hi = min(s + n, lo + per);
    float acc = 0.f;
    for (int i = lo; i < hi; ++i) acc += h2[(size_t)i * 128 + f];
    float inv = 1.0f / (float)max(n, 1);
    atomicAdd(&out[(size_t)g * OUT_W + f], acc * inv);
    if (c == 0) {
        float v = (n > 0) ? x2[(size_t)root_index[g] * 128 + f] : 0.f;
        out[(size_t)g * OUT_W + HID_F + f] = v;
    }
}

// ---------------- launch ----------------

static inline size_t align_up(size_t x, size_t a) { return (x + a - 1) / a * a; }

extern "C" void kernel_launch(void* const* d_in, const int* in_sizes, int n_in,
                              void* d_out, int out_size, void* d_ws, size_t ws_size,
                              hipStream_t stream) {
    const float* x = (const float*)d_in[0];
    const int* ei = (const int*)d_in[1];
    const int* batch = (const int*)d_in[2];
    const int* root = (const int*)d_in[3];
    const float* W1 = (const float*)d_in[4];
    const float* b1 = (const float*)d_in[5];
    const float* W2 = (const float*)d_in[6];
    const float* b2 = (const float*)d_in[7];
    float* out = (float*)d_out;

    const int* src = ei;
    const int* dst = ei + N_EDGES;

    // workspace carve-up
    char* ws = (char*)d_ws;
    size_t off = 0;
    const size_t NB = (size_t)N_NODES * 128 * sizeof(float); // 102.4 MB

    float* deg = (float*)(ws + off); off = align_up(off + (size_t)N_NODES * sizeof(float), 256);
    int* cnt = (int*)(ws + off);     off = align_up(off + N_GRAPHS * sizeof(int), 256);
    int* startv = (int*)(ws + off);  off = align_up(off + N_GRAPHS * sizeof(int), 256);
    float* rootlin = (float*)(ws + off); off = align_up(off + (size_t)N_GRAPHS * OUT_F * sizeof(float), 256);
    float* buf0 = (float*)(ws + off); off = align_up(off + NB, 256); // h0 -> hlin -> h2relu
    float* buf1 = (float*)(ws + off); off = align_up(off + NB, 256); // agg (both convs)
    float* buf2 = (float*)(ws + off); off = align_up(off + NB, 256); // x2
    (void)ws_size; (void)n_in; (void)in_sizes; (void)out_size;

    const int total4 = N_NODES * 32; // N*128/4

    // degree (with self loop) + segment bookkeeping (batch sorted -> binary search)
    fill1_kernel<<<(N_NODES + 255) / 256, 256, 0, stream>>>(deg, N_NODES);
    deg_edges_kernel<<<(N_EDGES + 255) / 256, 256, 0, stream>>>(dst, deg, N_EDGES);
    bounds_kernel<<<1, N_GRAPHS, 0, stream>>>(batch, startv, cnt, N_NODES, N_GRAPHS);

    // conv1: h0 = x @ W1
    {
        dim3 grid(N_NODES / 64, HID_F / 64);
        gemm_kernel<<<grid, 256, 0, stream>>>(x, W1, buf0, N_NODES, IN_F, HID_F, 0, nullptr, nullptr);
    }
    hipMemsetAsync(buf1, 0, NB, stream);
    scatter_kernel<<<(N_EDGES * 128) / 256, 256, 0, stream>>>(buf0, src, dst, deg, buf1, N_EDGES);
    finalize1_kernel<<<(total4 + 255) / 256, 256, 0, stream>>>(buf1, buf0, deg, b1, buf2, total4);

    // conv2: hlin = relu(x2) @ W2[0:128] + rootlin[batch]
    rootlin_kernel<<<N_GRAPHS, OUT_F, 0, stream>>>(x, root, W2, rootlin);
    {
        dim3 grid(N_NODES / 64, OUT_F / 64);
        gemm_kernel<<<grid, 256, 0, stream>>>(buf2, W2, buf0, N_NODES, HID_F, OUT_F, 1, rootlin, batch);
    }
    hipMemsetAsync(buf1, 0, NB, stream);
    scatter_kernel<<<(N_EDGES * 128) / 256, 256, 0, stream>>>(buf0, src, dst, deg, buf1, N_EDGES);
    finalize2_kernel<<<(total4 + 255) / 256, 256, 0, stream>>>(buf1, buf0, deg, b2, total4);

    // graph mean + root gather
    hipMemsetAsync(out, 0, (size_t)N_GRAPHS * OUT_W * sizeof(float), stream);
    dim3 mg(N_GRAPHS, 8);
    mean_kernel<<<mg, 128, 0, stream>>>(buf0, buf2, root, cnt, startv, out, 8);
}

// Round 3
// 714.968 us; speedup vs baseline: 2.1029x; 1.2631x over previous
//
#include <hip/hip_runtime.h>
#include <stddef.h>

// Problem constants (match reference setup_inputs)
constexpr int N_NODES = 200000;
constexpr int N_EDGES = 200000;
constexpr int N_GRAPHS = 128;
constexpr int IN_F = 256;
constexpr int HID_F = 128;
constexpr int OUT_F = 128;
constexpr int OUT_W = OUT_F + HID_F; // 256 output cols per graph

typedef __attribute__((ext_vector_type(8))) short short8;   // bf16x8 MFMA A/B frag
typedef __attribute__((ext_vector_type(4))) float float4v;  // fp32x4 MFMA C/D frag

__device__ __forceinline__ short f2bf(float f) {
    union { float f; unsigned u; } v; v.f = f;
    unsigned r = v.u + 0x7fffu + ((v.u >> 16) & 1u);  // RNE
    return (short)(r >> 16);
}

// ---------------- small utility kernels ----------------

__global__ void fill1_kernel(float* __restrict__ p, int n) {
    int i = blockIdx.x * blockDim.x + threadIdx.x;
    if (i < n) p[i] = 1.0f;
}

__global__ void deg_edges_kernel(const int* __restrict__ dst, float* __restrict__ deg, int E) {
    int e = blockIdx.x * blockDim.x + threadIdx.x;
    if (e < E) atomicAdd(&deg[dst[e]], 1.0f);
}

// deg -> rsqrt(deg) in place
__global__ void rsqrt_kernel(float* __restrict__ p, int n) {
    int i = blockIdx.x * blockDim.x + threadIdx.x;
    if (i < n) p[i] = rsqrtf(p[i]);
}

// batch is SORTED: segment bounds by binary search (R1 post-mortem: atomics were 582us)
__global__ void bounds_kernel(const int* __restrict__ batch, int* __restrict__ start,
                              int* __restrict__ cnt, int n, int G) {
    __shared__ int s_start[N_GRAPHS + 1];
    int g = threadIdx.x;
    if (g < G) {
        int lo = 0, hi = n;
        while (lo < hi) {
            int mid = (lo + hi) >> 1;
            if (batch[mid] < g) lo = mid + 1; else hi = mid;
        }
        s_start[g] = lo;
        if (g == 0) s_start[G] = n;
    }
    __syncthreads();
    if (g < G) {
        start[g] = s_start[g];
        cnt[g] = s_start[g + 1] - s_start[g];
    }
}

// Bt[n*K + k] = bf16(W[k*128 + n]) : pre-transpose weights into MFMA-B-friendly layout.
// grid K blocks x 128 threads; one-time ~100KB, pattern cost irrelevant.
__global__ void transpose_w_kernel(const float* __restrict__ W, short* __restrict__ Bt, int K) {
    int k = blockIdx.x;
    int n = threadIdx.x;
    Bt[(size_t)n * K + k] = f2bf(W[(size_t)k * 128 + n]);
}

// rootlin[g,f] = sum_k relu(x[root_index[g],k]) * W2[(HID_F+k)*OUT_F + f]
__global__ void rootlin_kernel(const float* __restrict__ x, const int* __restrict__ root_index,
                               const float* __restrict__ W2, float* __restrict__ rootlin)
{
    int g = blockIdx.x;
    int f = threadIdx.x; // OUT_F threads
    int r = root_index[g];
    const float* xr = x + (size_t)r * IN_F;
    float acc = 0.f;
    for (int k = 0; k < IN_F; ++k) {
        float xv = fmaxf(xr[k], 0.f);
        acc += xv * W2[(size_t)(HID_F + k) * OUT_F + f];
    }
    rootlin[(size_t)g * OUT_F + f] = acc;
}

// ---------------- bf16 MFMA GEMM ----------------
// C[M,128] = op(A)[M,KTOT] @ B[KTOT,128]; 64-row x 128-col block tile, 4 waves,
// each wave: 16 rows x 128 cols = 8 accumulators of 16x16.
// ATRANS: A element -> max(dinv[row]*a + bvec[k], 0)  (conv1 affine+relu fused in)
// ADDROOT: epilogue += rootlin[batch[row]][col] before dinv scaling
// Epilogue: v = dinv[row]*(acc [+ root]); double-write to out_src (scatter source)
// and out_acc (aggregator init = self-loop term), eliminating memset+finalize passes.
template<int KTOT, bool ATRANS, bool ADDROOT>
__global__ __launch_bounds__(256) void mfma_gemm_kernel(
    const float* __restrict__ A, const short* __restrict__ Bt,
    float* __restrict__ out_src, float* __restrict__ out_acc,
    const float* __restrict__ dinv, const float* __restrict__ bvec,
    const float* __restrict__ rootlin, const int* __restrict__ batch)
{
    // stride 136 shorts = 272B: bank stride 68 == 4 mod 32 -> 2-way conflicts only (free, m136)
    __shared__ __align__(16) short As[64][136];
    __shared__ __align__(16) short Bs[128][136];

    const int tid = threadIdx.x;
    const int wave = tid >> 6;
    const int lane = tid & 63;
    const int quad = lane >> 4;
    const int l16  = lane & 15;
    const int row0 = blockIdx.x * 64;

    float4v acc[8];
    #pragma unroll
    for (int c = 0; c < 8; ++c) acc[c] = (float4v){0.f, 0.f, 0.f, 0.f};

    // A staging: thread -> (row, 8-float column base), 4 iterations of 32-float stride
    const int arow = tid >> 2;
    const int ac8 = (tid & 3) * 8;
    float ascale = 1.0f;
    if (ATRANS) ascale = dinv[row0 + arow];

    // B staging: thread -> (n, 64-k half), 8 x short8
    const int bn = tid >> 1;
    const int bk = (tid & 1) * 64;

    for (int kb = 0; kb < KTOT / 128; ++kb) {
        // stage B chunk: Bs[n][k] = Bt[n][kb*128 + k]
        {
            const short* bp = Bt + (size_t)bn * KTOT + kb * 128 + bk;
            #pragma unroll
            for (int j = 0; j < 8; ++j)
                *(short8*)&Bs[bn][bk + 8 * j] = *(const short8*)(bp + 8 * j);
        }
        // stage A chunk (with optional fused affine+relu), fp32 -> bf16
        {
            const float* ap = A + (size_t)(row0 + arow) * KTOT + kb * 128 + ac8;
            #pragma unroll
            for (int jj = 0; jj < 4; ++jj) {
                float4 f0 = *(const float4*)(ap + 32 * jj);
                float4 f1 = *(const float4*)(ap + 32 * jj + 4);
                if (ATRANS) {
                    const float* bv = bvec + kb * 128 + ac8 + 32 * jj;
                    f0.x = fmaxf(ascale * f0.x + bv[0], 0.f);
                    f0.y = fmaxf(ascale * f0.y + bv[1], 0.f);
                    f0.z = fmaxf(ascale * f0.z + bv[2], 0.f);
                    f0.w = fmaxf(ascale * f0.w + bv[3], 0.f);
                    f1.x = fmaxf(ascale * f1.x + bv[4], 0.f);
                    f1.y = fmaxf(ascale * f1.y + bv[5], 0.f);
                    f1.z = fmaxf(ascale * f1.z + bv[6], 0.f);
                    f1.w = fmaxf(ascale * f1.w + bv[7], 0.f);
                }
                short8 s;
                s[0] = f2bf(f0.x); s[1] = f2bf(f0.y); s[2] = f2bf(f0.z); s[3] = f2bf(f0.w);
                s[4] = f2bf(f1.x); s[5] = f2bf(f1.y); s[6] = f2bf(f1.z); s[7] = f2bf(f1.w);
                *(short8*)&As[arow][ac8 + 32 * jj] = s;
            }
        }
        __syncthreads();
        #pragma unroll
        for (int ks = 0; ks < 4; ++ks) {
            // A frag: A[m=l16][k=ks*32+quad*8+j]  (m89-verified layout)
            short8 af = *(const short8*)&As[wave * 16 + l16][ks * 32 + quad * 8];
            #pragma unroll
            for (int c = 0; c < 8; ++c) {
                // B frag: B[k=ks*32+quad*8+j][n=c*16+l16]
                short8 bf = *(const short8*)&Bs[c * 16 + l16][ks * 32 + quad * 8];
                acc[c] = __builtin_amdgcn_mfma_f32_16x16x32_bf16(af, bf, acc[c], 0, 0, 0);
            }
        }
        __syncthreads();
    }

    // epilogue: D[row=quad*4+r][col=c*16+l16] (m89-verified C/D layout)
    #pragma unroll
    for (int r = 0; r < 4; ++r) {
        int row = row0 + wave * 16 + quad * 4 + r;
        float di = dinv[row];
        const float* rl = nullptr;
        if (ADDROOT) rl = rootlin + (size_t)batch[row] * 128;
        #pragma unroll
        for (int c = 0; c < 8; ++c) {
            int col = c * 16 + l16;
            float v = acc[c][r];
            if (ADDROOT) v += rl[col];
            v *= di;
            out_src[(size_t)row * 128 + col] = v;
            out_acc[(size_t)row * 128 + col] = v;
        }
    }
}

// agg[dst[e], f] += hs[src[e], f]  -- hs already dinv-scaled, agg pre-init with self term
__global__ __launch_bounds__(256) void scatter_kernel(
    const float* __restrict__ hs, const int* __restrict__ src, const int* __restrict__ dst,
    float* __restrict__ agg, int E)
{
    int t = blockIdx.x * 256 + threadIdx.x;
    int e = t >> 7;
    int f = t & 127;
    if (e >= E) return;
    atomicAdd(&agg[(size_t)dst[e] * 128 + f], hs[(size_t)src[e] * 128 + f]);
}

// out[g,0:128]   = (1/n) sum_seg relu(dinv[i]*agg2[i,f] + b2[f])   (finalize2 fused in)
// out[g,128:256] = n>0 ? dinv[root]*agg1[root,f] + b1[f] : 0       (x2[root] on the fly)
// grid (G, chunks) x 128 threads; out pre-zeroed.
__global__ void mean_kernel(const float* __restrict__ agg2, const float* __restrict__ agg1,
                            const float* __restrict__ dinv, const float* __restrict__ b1v,
                            const float* __restrict__ b2v, const int* __restrict__ root_index,
                            const int* __restrict__ cnt, const int* __restrict__ start,
                            float* __restrict__ out, int chunks)
{
    int g = blockIdx.x;
    int c = blockIdx.y;
    int f = threadIdx.x; // 128
    int s = start[g], n = cnt[g];
    int per = (n + chunks - 1) / chunks;
    int lo = s + c * per;
    int hi = min(s + n, lo + per);
    float bb = b2v[f];
    float accv = 0.f;
    for (int i = lo; i < hi; ++i)
        accv += fmaxf(dinv[i] * agg2[(size_t)i * 128 + f] + bb, 0.f);
    atomicAdd(&out[(size_t)g * OUT_W + f], accv / (float)max(n, 1));
    if (c == 0) {
        int r = root_index[g];
        float v = (n > 0) ? (dinv[r] * agg1[(size_t)r * 128 + f] + b1v[f]) : 0.f;
        out[(size_t)g * OUT_W + HID_F + f] = v;
    }
}

// ---------------- launch ----------------

static inline size_t align_up(size_t x, size_t a) { return (x + a - 1) / a * a; }

extern "C" void kernel_launch(void* const* d_in, const int* in_sizes, int n_in,
                              void* d_out, int out_size, void* d_ws, size_t ws_size,
                              hipStream_t stream) {
    const float* x = (const float*)d_in[0];
    const int* ei = (const int*)d_in[1];
    const int* batch = (const int*)d_in[2];
    const int* root = (const int*)d_in[3];
    const float* W1 = (const float*)d_in[4];
    const float* b1 = (const float*)d_in[5];
    const float* W2 = (const float*)d_in[6];
    const float* b2 = (const float*)d_in[7];
    float* out = (float*)d_out;

    const int* src = ei;
    const int* dst = ei + N_EDGES;

    // workspace carve-up
    char* ws = (char*)d_ws;
    size_t off = 0;
    const size_t NB = (size_t)N_NODES * 128 * sizeof(float); // 102.4 MB

    float* dinv = (float*)(ws + off);   off = align_up(off + (size_t)N_NODES * sizeof(float), 256);
    int* cnt = (int*)(ws + off);        off = align_up(off + N_GRAPHS * sizeof(int), 256);
    int* startv = (int*)(ws + off);     off = align_up(off + N_GRAPHS * sizeof(int), 256);
    float* rootlin = (float*)(ws + off); off = align_up(off + (size_t)N_GRAPHS * OUT_F * sizeof(float), 256);
    short* Bt1 = (short*)(ws + off);    off = align_up(off + (size_t)128 * IN_F * sizeof(short), 256);
    short* Bt2 = (short*)(ws + off);    off = align_up(off + (size_t)128 * HID_F * sizeof(short), 256);
    float* buf0 = (float*)(ws + off);   off = align_up(off + NB, 256); // hs1 then hs2 (scatter src)
    float* buf1 = (float*)(ws + off);   off = align_up(off + NB, 256); // agg1 (kept until mean)
    float* buf2 = (float*)(ws + off);   off = align_up(off + NB, 256); // agg2
    (void)ws_size; (void)n_in; (void)in_sizes; (void)out_size;

    // degree (with self loop) -> dinv = rsqrt(deg); segment bookkeeping
    fill1_kernel<<<(N_NODES + 255) / 256, 256, 0, stream>>>(dinv, N_NODES);
    deg_edges_kernel<<<(N_EDGES + 255) / 256, 256, 0, stream>>>(dst, dinv, N_EDGES);
    rsqrt_kernel<<<(N_NODES + 255) / 256, 256, 0, stream>>>(dinv, N_NODES);
    bounds_kernel<<<1, N_GRAPHS, 0, stream>>>(batch, startv, cnt, N_NODES, N_GRAPHS);

    // weight pre-transpose to bf16 [n][k]
    transpose_w_kernel<<<IN_F, 128, 0, stream>>>(W1, Bt1, IN_F);
    transpose_w_kernel<<<HID_F, 128, 0, stream>>>(W2, Bt2, HID_F); // first 128 rows of W2
    rootlin_kernel<<<N_GRAPHS, OUT_F, 0, stream>>>(x, root, W2, rootlin);

    // conv1: buf0 = buf1 = dinv .* (x @ W1)
    mfma_gemm_kernel<IN_F, false, false><<<N_NODES / 64, 256, 0, stream>>>(
        x, Bt1, buf0, buf1, dinv, nullptr, nullptr, nullptr);
    scatter_kernel<<<(N_EDGES * 128) / 256, 256, 0, stream>>>(buf0, src, dst, buf1, N_EDGES);

    // conv2: A = relu(dinv.*agg1 + b1) staged from buf1; += rootlin; dinv-prescale; double-write
    mfma_gemm_kernel<HID_F, true, true><<<N_NODES / 64, 256, 0, stream>>>(
        buf1, Bt2, buf0, buf2, dinv, b1, rootlin, batch);
    scatter_kernel<<<(N_EDGES * 128) / 256, 256, 0, stream>>>(buf0, src, dst, buf2, N_EDGES);

    // fused finalize2 + graph mean + root gather
    hipMemsetAsync(out, 0, (size_t)N_GRAPHS * OUT_W * sizeof(float), stream);
    dim3 mg(N_GRAPHS, 8);
    mean_kernel<<<mg, 128, 0, stream>>>(buf2, buf1, dinv, b1, b2, root, cnt, startv, out, 8);
}